// Round 1
// baseline (1264.744 us; speedup 1.0000x reference)
//
#include <hip/hip_runtime.h>
#include <hip/hip_bf16.h>
#include <float.h>

#define BB 512
#define TT 40
#define CC 512
#define HH 512

typedef short bf16x8 __attribute__((ext_vector_type(8)));
typedef float f32x4 __attribute__((ext_vector_type(4)));
typedef unsigned short ushortx8 __attribute__((ext_vector_type(8)));

__device__ __forceinline__ unsigned short f2bf(float f){
  union { float f; unsigned int i; } v; v.f = f;
  unsigned int r = v.i + 0x7fffu + ((v.i >> 16) & 1u);
  return (unsigned short)(r >> 16);
}

// one wave per (b,t): convert 512 floats -> bf16, compute nonzero mask
__global__ void prep_x_kernel(const float* __restrict__ x, unsigned short* __restrict__ xb,
                              float* __restrict__ mask){
  int w = blockIdx.x*4 + (threadIdx.x>>6);
  int lane = threadIdx.x & 63;
  const float* src = x + (size_t)w*CC + lane*8;
  f32x4 a = *(const f32x4*)(src);
  f32x4 b = *(const f32x4*)(src+4);
  ushortx8 o;
  o[0]=f2bf(a[0]); o[1]=f2bf(a[1]); o[2]=f2bf(a[2]); o[3]=f2bf(a[3]);
  o[4]=f2bf(b[0]); o[5]=f2bf(b[1]); o[6]=f2bf(b[2]); o[7]=f2bf(b[3]);
  *(ushortx8*)(xb + (size_t)w*CC + lane*8) = o;
  bool nz = (a[0]!=0.f)||(a[1]!=0.f)||(a[2]!=0.f)||(a[3]!=0.f)||
            (b[0]!=0.f)||(b[1]!=0.f)||(b[2]!=0.f)||(b[3]!=0.f);
  unsigned long long bal = __ballot(nz);
  if (lane==0) mask[w] = bal ? 1.0f : 0.0f;
}

__global__ void cvt_kernel(const float* __restrict__ src, unsigned short* __restrict__ dst, int n){
  int i = blockIdx.x*blockDim.x + threadIdx.x;
  if (i < n) dst[i] = f2bf(src[i]);
}

// zero h buffers (fp32 + bf16), init out to -FLT_MAX. grid*block == 2*2*BB*HH exactly.
__global__ void init_kernel(float* __restrict__ h32, unsigned short* __restrict__ hb,
                            float* __restrict__ out){
  int i = blockIdx.x*blockDim.x + threadIdx.x;
  h32[i] = 0.f;
  hb[i] = 0;
  if (i < BB*2*HH) out[i] = -FLT_MAX;
}

// One GRU timestep, both directions (blockIdx.z). Tile: 64 batch rows x 64 h cols.
// 4 waves, each 32x32. Four accumulator groups: r, z, n_x, n_h.
__global__ __launch_bounds__(256) void gru_step_kernel(
    const unsigned short* __restrict__ xb,
    const unsigned short* __restrict__ wihF, const unsigned short* __restrict__ whhF,
    const unsigned short* __restrict__ wihB, const unsigned short* __restrict__ whhB,
    const float* __restrict__ bihF, const float* __restrict__ bhhF,
    const float* __restrict__ bihB, const float* __restrict__ bhhB,
    const float* __restrict__ mask,
    float* __restrict__ h32, unsigned short* __restrict__ hb,
    float* __restrict__ out, int t)
{
  const int dir = blockIdx.z;
  const int tx = dir ? (TT-1-t) : t;
  const unsigned short* wih = dir ? wihB : wihF;
  const unsigned short* whh = dir ? whhB : whhF;
  const float* bih = dir ? bihB : bihF;
  const float* bhh = dir ? bhhB : bhhF;
  const int bufin = t & 1;
  const float* hin  = h32 + (size_t)(dir*2+bufin)*BB*HH;
  float* hout       = h32 + (size_t)(dir*2+(bufin^1))*BB*HH;
  const unsigned short* hbin = hb + (size_t)(dir*2+bufin)*BB*HH;
  unsigned short* hbout      = hb + (size_t)(dir*2+(bufin^1))*BB*HH;
  const int b0 = blockIdx.x*64;
  const int n0 = blockIdx.y*64;

  // LDS: As_x[64][32] | As_h[64][32] | 6 weight panels [64][32] each = 32KB
  __shared__ __align__(16) unsigned short smem[512*32];

  const int tid = threadIdx.x;
  const int lane = tid & 63;
  const int wv = tid >> 6;
  const int r0 = (wv>>1)*32;
  const int c0 = (wv&1)*32;
  const int lr = lane & 15;
  const int lk = (lane>>4)*8;

  f32x4 accr[2][2], accz[2][2], accnx[2][2], accnh[2][2];
  #pragma unroll
  for (int i=0;i<2;++i)
    #pragma unroll
    for (int j=0;j<2;++j){ accr[i][j]=0.f; accz[i][j]=0.f; accnx[i][j]=0.f; accnh[i][j]=0.f; }

  const int srow = tid >> 2;        // 0..63
  const int skb  = (tid & 3) * 8;   // 0,8,16,24

  for (int kk=0; kk<16; ++kk){
    const int k0 = kk*32;
    // ---- stage to LDS (reg round-trip; simple & correct this round) ----
    *(ushortx8*)(smem + tid*8) =
        *(const ushortx8*)(xb + ((size_t)(b0+srow)*TT + tx)*CC + k0 + skb);
    *(ushortx8*)(smem + 2048 + tid*8) =
        *(const ushortx8*)(hbin + (size_t)(b0+srow)*HH + k0 + skb);
    #pragma unroll
    for (int p=0;p<6;++p){
      const unsigned short* w = (p>=3) ? whh : wih;
      const int g = (p>=3) ? (p-3) : p;
      *(ushortx8*)(smem + 4096 + p*2048 + tid*8) =
          *(const ushortx8*)(w + (size_t)(g*HH + n0 + srow)*CC + k0 + skb);
    }
    __syncthreads();
    // ---- fragments ----
    bf16x8 ax[2], ah[2];
    #pragma unroll
    for (int mf=0;mf<2;++mf){
      ax[mf] = *(const bf16x8*)(smem + ((r0+mf*16+lr)*32 + lk));
      ah[mf] = *(const bf16x8*)(smem + 2048 + ((r0+mf*16+lr)*32 + lk));
    }
    bf16x8 bw[6][2];
    #pragma unroll
    for (int p=0;p<6;++p)
      #pragma unroll
      for (int nf=0;nf<2;++nf)
        bw[p][nf] = *(const bf16x8*)(smem + 4096 + p*2048 + ((c0+nf*16+lr)*32 + lk));
    // ---- MFMAs ----
    #pragma unroll
    for (int mf=0;mf<2;++mf)
      #pragma unroll
      for (int nf=0;nf<2;++nf){
        accr[mf][nf]  = __builtin_amdgcn_mfma_f32_16x16x32_bf16(ax[mf], bw[0][nf], accr[mf][nf],0,0,0);
        accr[mf][nf]  = __builtin_amdgcn_mfma_f32_16x16x32_bf16(ah[mf], bw[3][nf], accr[mf][nf],0,0,0);
        accz[mf][nf]  = __builtin_amdgcn_mfma_f32_16x16x32_bf16(ax[mf], bw[1][nf], accz[mf][nf],0,0,0);
        accz[mf][nf]  = __builtin_amdgcn_mfma_f32_16x16x32_bf16(ah[mf], bw[4][nf], accz[mf][nf],0,0,0);
        accnx[mf][nf] = __builtin_amdgcn_mfma_f32_16x16x32_bf16(ax[mf], bw[2][nf], accnx[mf][nf],0,0,0);
        accnh[mf][nf] = __builtin_amdgcn_mfma_f32_16x16x32_bf16(ah[mf], bw[5][nf], accnh[mf][nf],0,0,0);
      }
    __syncthreads();
  }

  // ---- epilogue: gates, h update, masked max-pool ----
  #pragma unroll
  for (int mf=0;mf<2;++mf){
    #pragma unroll
    for (int nf=0;nf<2;++nf){
      const int jj = n0 + c0 + nf*16 + lr;
      const float br  = bih[jj] + bhh[jj];
      const float bz  = bih[HH+jj] + bhh[HH+jj];
      const float bnx = bih[2*HH+jj];
      const float bnh = bhh[2*HH+jj];
      #pragma unroll
      for (int j=0;j<4;++j){
        const int m = r0 + mf*16 + (lane>>4)*4 + j;
        const int b = b0 + m;
        const float rg = 1.f/(1.f + __expf(-(accr[mf][nf][j] + br)));
        const float zg = 1.f/(1.f + __expf(-(accz[mf][nf][j] + bz)));
        const float ng = tanhf(accnx[mf][nf][j] + bnx + rg*(accnh[mf][nf][j] + bnh));
        const float hp = hin[(size_t)b*HH + jj];
        const float hn = (1.f - zg)*ng + zg*hp;
        hout[(size_t)b*HH + jj] = hn;
        hbout[(size_t)b*HH + jj] = f2bf(hn);
        if (mask[b*TT + tx] != 0.f){
          float* o = out + (size_t)b*(2*HH) + dir*HH + jj;
          const float cur = *o;
          *o = hn > cur ? hn : cur;
        }
      }
    }
  }
}

extern "C" void kernel_launch(void* const* d_in, const int* in_sizes, int n_in,
                              void* d_out, int out_size, void* d_ws, size_t ws_size,
                              hipStream_t stream) {
  const float* x    = (const float*)d_in[0];
  const float* WihF = (const float*)d_in[1];
  const float* WhhF = (const float*)d_in[2];
  const float* bihF = (const float*)d_in[3];
  const float* bhhF = (const float*)d_in[4];
  const float* WihB = (const float*)d_in[5];
  const float* WhhB = (const float*)d_in[6];
  const float* bihB = (const float*)d_in[7];
  const float* bhhB = (const float*)d_in[8];
  float* out = (float*)d_out;

  char* ws = (char*)d_ws;
  unsigned short* xb    = (unsigned short*)(ws);              // B*T*C bf16 = 20,971,520 B
  unsigned short* wb    = (unsigned short*)(ws + 20971520);   // 4 * 786432 bf16
  unsigned short* wihFb = wb;
  unsigned short* whhFb = wb + 786432;
  unsigned short* wihBb = wb + 2*786432;
  unsigned short* whhBb = wb + 3*786432;
  float* mask = (float*)(ws + 27262976);                      // B*T floats
  float* h32  = (float*)(ws + 27344896);                      // [2dir][2buf][B][H] f32
  unsigned short* hb = (unsigned short*)(ws + 31539200);      // [2dir][2buf][B][H] bf16

  prep_x_kernel<<<BB*TT/4, 256, 0, stream>>>(x, xb, mask);
  cvt_kernel<<<3072, 256, 0, stream>>>(WihF, wihFb, 786432);
  cvt_kernel<<<3072, 256, 0, stream>>>(WhhF, whhFb, 786432);
  cvt_kernel<<<3072, 256, 0, stream>>>(WihB, wihBb, 786432);
  cvt_kernel<<<3072, 256, 0, stream>>>(WhhB, whhBb, 786432);
  init_kernel<<<4096, 256, 0, stream>>>(h32, hb, out);

  dim3 grid(BB/64, HH/64, 2);
  for (int t=0; t<TT; ++t){
    gru_step_kernel<<<grid, 256, 0, stream>>>(xb, wihFb, whhFb, wihBb, whhBb,
                                              bihF, bhhF, bihB, bhhB,
                                              mask, h32, hb, out, t);
  }
}